// Round 2
// 2425.538 us; speedup vs baseline: 1.1722x; 1.1722x over previous
//
#include <hip/hip_runtime.h>
#include <math.h>

// ============================================================================
// Round 3 (resubmit; round-1 run died to container-acquire failure, no counters).
// Deform path restructured:
//   - K reordered to kyx-major (kk = kyx*256 + c): sampler output is contiguous
//     in K -> ds_write_b128 instead of 32x ds_write_b16 per pair.
//   - Bilinear metadata (4 weights f32 + 4 row idx u16) precomputed ONCE per
//     (pix,kyx) into LDS.
//   - Double-buffered value tile (2x32KB), 1 barrier/kyx, sample(k+1) issued
//     before MFMA(k) -> gather latency hides under 128 MFMAs.
//   - __launch_bounds__(256,2): 256-VGPR budget for memory-level parallelism
//     (old kernel compiled to 64 VGPRs -> ~4 loads in flight -> stall-bound).
//   - z + x merged into one dispatch (640 blocks) to kill z's half-idle chip.
//   - Epilogue: per-wave LDS transpose -> global_store_dwordx4 (256B segments).
//   - energy/softmax/cam_use/offset unchanged (offset merged z+x only).
// ============================================================================

#define BB 32

typedef _Float16 f16x8 __attribute__((ext_vector_type(8)));
typedef float    f32x4 __attribute__((ext_vector_type(4)));

// ---------- prep: weight fragment swizzle + offset-weight transpose ----------
// WTs fragment order: for ks in [0,72), ot in [0,16), lane in [0,64), j in [0,8):
//   frag-K kk = ks*32 + (lane>>4)*8 + j, interpreted kyx-major: kyx=kk>>8, c=kk&255
//   WTs[((ks*16+ot)*64+lane)*8+j] = f16( dw[o=ot*16+(lane&15)][c][kyx] )
__global__ void prep_kernel(const float* __restrict__ dw,
                            const float* __restrict__ offw,
                            _Float16* __restrict__ WTs,   // [589824]
                            float* __restrict__ offwP) {  // [9][18][256]
    int bx = blockIdx.x;
    int t  = threadIdx.x;
    if (bx < 2304) {
        int idx = bx * 256 + t;
        int j    = idx & 7;
        int lane = (idx >> 3) & 63;
        int ot   = (idx >> 9) & 15;
        int ks   = idx >> 13;
        int o  = ot * 16 + (lane & 15);
        int kk = ks * 32 + (lane >> 4) * 8 + j;      // kyx-major K index
        int c   = kk & 255;
        int kyx = kk >> 8;
        WTs[idx] = (_Float16)dw[(size_t)o * 2304 + c * 9 + kyx];
    } else {
        int r = bx - 2304;            // [0,162): kyx*18 + j
        int kyx = r / 18, j = r % 18;
        offwP[((size_t)(kyx * 18 + j)) * 256 + t] = offw[((size_t)(j * 256 + t)) * 9 + kyx];
    }
}

// ---------- energy: E[b,c,d] = sum_n f[c,n] f[d,n] ----------
__global__ void energy_kernel(const float* __restrict__ f,
                              float* __restrict__ energy, int N) {
    int b  = blockIdx.z;
    int c0 = blockIdx.x * 64;
    int d0 = blockIdx.y * 64;
    int t  = threadIdx.x;
    __shared__ __align__(16) float A[32][68];
    __shared__ __align__(16) float Bs[32][68];
    float acc[4][4] = {};
    int cc0 = (t & 15) * 4;
    int dd0 = (t >> 4) * 4;
    const float* fb = f + (size_t)b * 256 * N;
    for (int n0 = 0; n0 < N; n0 += 32) {
        #pragma unroll
        for (int pass = 0; pass < 8; ++pass) {
            int idx = pass * 256 + t;
            int nn = idx & 31;
            int rr = idx >> 5;
            int n = n0 + nn;
            float va = (n < N) ? fb[(size_t)(c0 + rr) * N + n] : 0.f;
            float vb = (n < N) ? fb[(size_t)(d0 + rr) * N + n] : 0.f;
            A[nn][rr]  = va;
            Bs[nn][rr] = vb;
        }
        __syncthreads();
        #pragma unroll 8
        for (int nn = 0; nn < 32; ++nn) {
            float4 a4 = *(const float4*)&A[nn][cc0];
            float4 b4 = *(const float4*)&Bs[nn][dd0];
            float av[4] = {a4.x, a4.y, a4.z, a4.w};
            float bv[4] = {b4.x, b4.y, b4.z, b4.w};
            #pragma unroll
            for (int i = 0; i < 4; ++i)
                #pragma unroll
                for (int j = 0; j < 4; ++j)
                    acc[i][j] += av[i] * bv[j];
        }
        __syncthreads();
    }
    #pragma unroll
    for (int i = 0; i < 4; ++i) {
        float4 o4 = {acc[i][0], acc[i][1], acc[i][2], acc[i][3]};
        *(float4*)&energy[((size_t)b * 256 + (c0 + cc0 + i)) * 256 + d0 + dd0] = o4;
    }
}

// ---------- softmax over rows: attn = exp(min - e) / sum ----------
__global__ void softmax_kernel(float* __restrict__ attn) {
    int row = blockIdx.x;
    int t = threadIdx.x;
    float e = attn[(size_t)row * 256 + t];
    __shared__ float red[256];
    red[t] = e;
    __syncthreads();
    for (int s = 128; s > 0; s >>= 1) {
        if (t < s) red[t] = fminf(red[t], red[t + s]);
        __syncthreads();
    }
    float mn = red[0];
    __syncthreads();
    float p = __expf(mn - e);
    red[t] = p;
    __syncthreads();
    for (int s = 128; s > 0; s >>= 1) {
        if (t < s) red[t] += red[t + s];
        __syncthreads();
    }
    float inv = 1.f / red[0];
    attn[(size_t)row * 256 + t] = p * inv;
}

// ---------- cam_use (cross attn), channel-last output ----------
__global__ void cam_use_kernel(const float* __restrict__ f,
                               const float* __restrict__ attn,
                               const float* __restrict__ gamma,
                               float* __restrict__ g, int N) {
    int b  = blockIdx.z;
    int n0 = blockIdx.x * 64;
    int c0 = blockIdx.y * 64;
    int t  = threadIdx.x;
    __shared__ __align__(16) float At[32][68];
    __shared__ __align__(16) float Ft[32][68];
    float acc[4][4] = {};
    int cc0 = (t & 15) * 4;
    int nn0 = (t >> 4) * 4;
    const float* fb = f + (size_t)b * 256 * N;
    const float* ab = attn + (size_t)b * 256 * 256;
    for (int d0 = 0; d0 < 256; d0 += 32) {
        #pragma unroll
        for (int pass = 0; pass < 8; ++pass) {
            int idx = pass * 256 + t;
            int dd = idx & 31;
            int cc = idx >> 5;
            At[dd][cc] = ab[(size_t)(c0 + cc) * 256 + d0 + dd];
        }
        #pragma unroll
        for (int pass = 0; pass < 8; ++pass) {
            int idx = pass * 256 + t;
            int nn = idx & 63;
            int dd = idx >> 6;
            int n = n0 + nn;
            Ft[dd][nn] = (n < N) ? fb[(size_t)(d0 + dd) * N + n] : 0.f;
        }
        __syncthreads();
        #pragma unroll 8
        for (int dd = 0; dd < 32; ++dd) {
            float4 a4 = *(const float4*)&At[dd][cc0];
            float4 f4 = *(const float4*)&Ft[dd][nn0];
            float av[4] = {a4.x, a4.y, a4.z, a4.w};
            float fv[4] = {f4.x, f4.y, f4.z, f4.w};
            #pragma unroll
            for (int i = 0; i < 4; ++i)
                #pragma unroll
                for (int j = 0; j < 4; ++j)
                    acc[i][j] += av[i] * fv[j];
        }
        __syncthreads();
    }
    float gam = gamma[0];
    #pragma unroll
    for (int j = 0; j < 4; ++j) {
        int n = n0 + nn0 + j;
        if (n >= N) continue;
        float4 o4;
        o4.x = fb[(size_t)(c0 + cc0 + 0) * N + n] + gam * acc[0][j];
        o4.y = fb[(size_t)(c0 + cc0 + 1) * N + n] + gam * acc[1][j];
        o4.z = fb[(size_t)(c0 + cc0 + 2) * N + n] + gam * acc[2][j];
        o4.w = fb[(size_t)(c0 + cc0 + 3) * N + n] + gam * acc[3][j];
        *(float4*)&g[((size_t)b * N + n) * 256 + c0 + cc0] = o4;
    }
}

// ---------- offset conv: pyx[b][pix][18] = base + conv18(g), z+x merged ----------
__global__ void offset_kernel(const float* __restrict__ gx_,
                              const float* __restrict__ gz_,
                              const float* __restrict__ offwP,   // [9][18][256]
                              const float* __restrict__ offb,    // [18]
                              float* __restrict__ pyxx_,
                              float* __restrict__ pyxz_) {
    const int bx = blockIdx.x;
    const float* g; float* pyxg; int H, W, p0;
    if (bx < 16) { g = gx_; pyxg = pyxx_; H = 31; W = 31; p0 = bx * 64; }
    else         { g = gz_; pyxg = pyxz_; H = 15; W = 15; p0 = (bx - 16) * 64; }
    const int N = H * W;
    const int b  = blockIdx.y;
    const int t  = threadIdx.x;
    const int pixl = t & 63;
    const int q = __builtin_amdgcn_readfirstlane(t >> 6);  // channel quarter
    const int pix = p0 + pixl;
    float acc[18];
    #pragma unroll
    for (int j = 0; j < 18; ++j) acc[j] = 0.f;
    const float* gb = g + (size_t)b * N * 256;
    if (pix < N) {
        int h = pix / W, w_ = pix % W;
        for (int kyx = 0; kyx < 9; ++kyx) {
            int y = h + kyx / 3 - 1;
            int x = w_ + kyx % 3 - 1;
            if (y < 0 || y >= H || x < 0 || x >= W) continue;
            const float* grow = gb + (size_t)(y * W + x) * 256 + q * 64;
            const float* wrow = offwP + (size_t)kyx * 18 * 256 + q * 64;
            for (int c4 = 0; c4 < 16; ++c4) {
                float4 g4 = *(const float4*)(grow + c4 * 4);
                #pragma unroll
                for (int j = 0; j < 18; ++j) {
                    float4 w4 = *(const float4*)(wrow + (size_t)j * 256 + c4 * 4);
                    acc[j] += g4.x * w4.x + g4.y * w4.y + g4.z * w4.z + g4.w * w4.w;
                }
            }
        }
    }
    __shared__ float red[4][64][18];
    #pragma unroll
    for (int j = 0; j < 18; ++j) red[q][pixl][j] = acc[j];
    __syncthreads();
    for (int idx = t; idx < 64 * 18; idx += 256) {
        int pl = idx / 18, j = idx % 18;
        int pp = p0 + pl;
        if (pp >= N) continue;
        float s = red[0][pl][j] + red[1][pl][j] + red[2][pl][j] + red[3][pl][j] + offb[j];
        int k = j >> 1, comp = j & 1;
        int h = pp / W, w_ = pp % W;
        float base = comp ? (float)(w_ + (k % 3) - 1) : (float)(h + (k / 3) - 1);
        pyxg[((size_t)b * N + pp) * 18 + j] = base + s;
    }
}

// ---------- deform: kyx-major K, double-buffered sample->MFMA pipeline ----------
__global__ __launch_bounds__(256, 2)
void deform_mfma_kernel(const float* __restrict__ gx_,
                        const float* __restrict__ gz_,
                        const _Float16* __restrict__ WTs,   // frag order, kyx-major K
                        const float* __restrict__ pyxx_,
                        const float* __restrict__ pyxz_,
                        float* __restrict__ outx_,
                        float* __restrict__ outz_) {
    const int bx = blockIdx.x;
    const int b  = blockIdx.y;
    const float* g; const float* pyxg; float* out; int H, W, p0;
    if (bx < 16) { g = gx_; pyxg = pyxx_; out = outx_; H = 31; W = 31; p0 = bx * 64; }
    else         { g = gz_; pyxg = pyxz_; out = outz_; H = 15; W = 15; p0 = (bx - 16) * 64; }
    const int N = H * W;
    const int t    = threadIdx.x;
    const int lane = t & 63;
    const int wv   = t >> 6;

    // LDS: 2x32KB value tiles + 13.8KB meta = 77.5KB -> 2 blocks/CU
    __shared__ __align__(16) _Float16 valq[2][32 * 64 * 8];
    __shared__ __align__(16) float4  metaW[576];   // per (pixl,kyx): w00,w01,w10,w11
    __shared__ __align__(8)  ushort4 metaR[576];   // per (pixl,kyx): 4 clamped row idx

    const float* gb = g + (size_t)b * N * 256;
    const float Hm1 = (float)(H - 1), Wm1 = (float)(W - 1);

    // ---- metadata phase: one pass, reused by all 9 kyx iterations ----
    for (int idx = t; idx < 576; idx += 256) {
        int pixl = idx / 9, kyx = idx - pixl * 9;
        int pix = p0 + pixl;
        float py = -1.0e6f, px = -1.0e6f;
        if (pix < N) {
            const float* pp = pyxg + ((size_t)b * N + pix) * 18 + kyx * 2;
            py = pp[0]; px = pp[1];
        }
        float y0f = floorf(py), x0f = floorf(px);
        float fy = py - y0f, fx = px - x0f;
        bool vy0 = (y0f >= 0.f) && (y0f <= Hm1);
        bool vy1 = (y0f + 1.f >= 0.f) && (y0f + 1.f <= Hm1);
        bool vx0 = (x0f >= 0.f) && (x0f <= Wm1);
        bool vx1 = (x0f + 1.f >= 0.f) && (x0f + 1.f <= Wm1);
        int iy0 = min(max((int)y0f, 0), H - 1);
        int iy1 = min(max((int)y0f + 1, 0), H - 1);
        int ix0 = min(max((int)x0f, 0), W - 1);
        int ix1 = min(max((int)x0f + 1, 0), W - 1);
        float w00 = (vy0 && vx0) ? (1.f - fy) * (1.f - fx) : 0.f;
        float w01 = (vy0 && vx1) ? (1.f - fy) * fx : 0.f;
        float w10 = (vy1 && vx0) ? fy * (1.f - fx) : 0.f;
        float w11 = (vy1 && vx1) ? fy * fx : 0.f;
        metaW[idx] = make_float4(w00, w01, w10, w11);
        metaR[idx] = make_ushort4((unsigned short)(iy0 * W + ix0),
                                  (unsigned short)(iy0 * W + ix1),
                                  (unsigned short)(iy1 * W + ix0),
                                  (unsigned short)(iy1 * W + ix1));
    }

    f32x4 acc[4][4];
    #pragma unroll
    for (int i = 0; i < 4; ++i)
        #pragma unroll
        for (int j = 0; j < 4; ++j)
            acc[i][j] = (f32x4){0.f, 0.f, 0.f, 0.f};

    // sample one kyx plane (64px x 256ch) into valq[bufsel]; b128 LDS writes
    auto SAMPLE = [&](int kyx, int bufsel) {
        _Float16* vq = &valq[bufsel][0];
        #pragma unroll
        for (int s = 0; s < 2; ++s) {
            int item = t + s * 256;          // 512 items: (pix, 32ch-block)
            int pixl = item >> 3;
            int cb   = item & 7;
            float4  w4 = metaW[pixl * 9 + kyx];
            ushort4 r4 = metaR[pixl * 9 + kyx];
            const float* p00 = gb + (size_t)r4.x * 256 + cb * 32;
            const float* p01 = gb + (size_t)r4.y * 256 + cb * 32;
            const float* p10 = gb + (size_t)r4.z * 256 + cb * 32;
            const float* p11 = gb + (size_t)r4.w * 256 + cb * 32;
            #pragma unroll
            for (int gq = 0; gq < 4; ++gq) {
                float4 a0 = *(const float4*)(p00 + gq * 8);
                float4 a1 = *(const float4*)(p00 + gq * 8 + 4);
                float4 b0 = *(const float4*)(p01 + gq * 8);
                float4 b1 = *(const float4*)(p01 + gq * 8 + 4);
                float4 c0 = *(const float4*)(p10 + gq * 8);
                float4 c1 = *(const float4*)(p10 + gq * 8 + 4);
                float4 d0 = *(const float4*)(p11 + gq * 8);
                float4 d1 = *(const float4*)(p11 + gq * 8 + 4);
                float va[8] = {a0.x, a0.y, a0.z, a0.w, a1.x, a1.y, a1.z, a1.w};
                float vb[8] = {b0.x, b0.y, b0.z, b0.w, b1.x, b1.y, b1.z, b1.w};
                float vc[8] = {c0.x, c0.y, c0.z, c0.w, c1.x, c1.y, c1.z, c1.w};
                float vd[8] = {d0.x, d0.y, d0.z, d0.w, d1.x, d1.y, d1.z, d1.w};
                f16x8 h;
                #pragma unroll
                for (int j = 0; j < 8; ++j)
                    h[j] = (_Float16)(w4.x * va[j] + w4.y * vb[j] +
                                      w4.z * vc[j] + w4.w * vd[j]);
                *(f16x8*)&vq[((cb * 4 + gq) * 64 + pixl) * 8] = h;
            }
        }
    };

    // 8 K-steps (K=32 each) over one kyx plane
    auto MFMA9 = [&](int kyx, int bufsel) {
        const _Float16* vq = &valq[bufsel][0];
        #pragma unroll 4
        for (int cs = 0; cs < 8; ++cs) {
            int ks = kyx * 8 + cs;
            f16x8 afrag[4], bfrag[4];
            #pragma unroll
            for (int ot = 0; ot < 4; ++ot)
                afrag[ot] = *(const f16x8*)(WTs +
                    (((size_t)ks * 16 + wv * 4 + ot) * 64 + lane) * 8);
            #pragma unroll
            for (int pt = 0; pt < 4; ++pt)
                bfrag[pt] = *(const f16x8*)(vq +
                    (((cs * 4 + (lane >> 4)) * 64) + pt * 16 + (lane & 15)) * 8);
            #pragma unroll
            for (int ot = 0; ot < 4; ++ot)
                #pragma unroll
                for (int pt = 0; pt < 4; ++pt)
                    acc[ot][pt] = __builtin_amdgcn_mfma_f32_16x16x32_f16(
                        afrag[ot], bfrag[pt], acc[ot][pt], 0, 0, 0);
        }
    };

    __syncthreads();          // meta visible
    SAMPLE(0, 0);
    for (int kyx = 0; kyx < 9; ++kyx) {
        __syncthreads();      // sample(kyx) complete; MFMA(kyx-1) done
        if (kyx < 8) SAMPLE(kyx + 1, (kyx + 1) & 1);  // loads in flight over MFMA
        MFMA9(kyx, kyx & 1);
    }

    // ---- epilogue: per-wave LDS transpose -> 16B coalesced stores ----
    __syncthreads();          // valq free for reuse
    float* tp = (float*)&valq[0][0] + wv * 4096;   // 64o x 64px per wave
    const int pcol = lane & 15;
    const int quad = lane >> 4;
    #pragma unroll
    for (int ot = 0; ot < 4; ++ot)
        #pragma unroll
        for (int pt = 0; pt < 4; ++pt)
            #pragma unroll
            for (int r = 0; r < 4; ++r)
                tp[(ot * 16 + quad * 4 + r) * 64 + pt * 16 + pcol] = acc[ot][pt][r];
    // per-wave region: compiler-inserted lgkmcnt handles the RAW dependency
    float* ob = out + (size_t)b * 256 * N;
    #pragma unroll
    for (int i = 0; i < 16; ++i) {
        int o   = wv * 64 + i * 4 + quad;
        int px0 = p0 + pcol * 4;
        float4 v = *(const float4*)&tp[(i * 4 + quad) * 64 + pcol * 4];
        if (px0 + 3 < N) {
            *(float4*)&ob[(size_t)o * N + px0] = v;
        } else if (px0 < N) {
            float vv[4] = {v.x, v.y, v.z, v.w};
            #pragma unroll
            for (int j = 0; j < 4; ++j)
                if (px0 + j < N) ob[(size_t)o * N + px0 + j] = vv[j];
        }
    }
}

extern "C" void kernel_launch(void* const* d_in, const int* in_sizes, int n_in,
                              void* d_out, int out_size, void* d_ws, size_t ws_size,
                              hipStream_t stream) {
    const int Nz = 225, Nx = 961;
    const size_t ZSZ = (size_t)BB * 256 * Nz;
    const size_t XSZ = (size_t)BB * 256 * Nx;

    bool dict_order = (in_sizes[1] == (int)XSZ);
    const float *z[3], *x[3], *offw[3], *offb[3], *dw[3], *gamma[3];
    for (int i = 0; i < 3; ++i) {
        if (dict_order) {
            z[i]     = (const float*)d_in[i * 6 + 0];
            x[i]     = (const float*)d_in[i * 6 + 1];
            offw[i]  = (const float*)d_in[i * 6 + 2];
            offb[i]  = (const float*)d_in[i * 6 + 3];
            dw[i]    = (const float*)d_in[i * 6 + 4];
            gamma[i] = (const float*)d_in[i * 6 + 5];
        } else {
            z[i]     = (const float*)d_in[i];
            x[i]     = (const float*)d_in[3 + i];
            offw[i]  = (const float*)d_in[6 + i * 4 + 0];
            offb[i]  = (const float*)d_in[6 + i * 4 + 1];
            dw[i]    = (const float*)d_in[6 + i * 4 + 2];
            gamma[i] = (const float*)d_in[6 + i * 4 + 3];
        }
    }

    // workspace layout (floats)
    float* ws = (float*)d_ws;
    _Float16* WTs3 = (_Float16*)ws;          // 3*589824 f16 = 884736 floats
    float* offwP3 = ws + 884736;             // 3*41472
    float* attn_z = offwP3 + 3 * 41472;      // 2097152
    float* attn_x = attn_z + 2097152;        // 2097152
    float* gz     = attn_x + 2097152;        // 1843200
    float* gx     = gz + 1843200;            // 7872512
    float* pyz    = gx + 7872512;            // 32*225*18 = 129600
    float* pyxx   = pyz + 129600;            // 32*961*18 = 553536
    // total 15,602,304 floats = 62.4 MB

    for (int i = 0; i < 3; ++i)
        prep_kernel<<<2466, 256, 0, stream>>>(dw[i], offw[i],
                                              WTs3 + (size_t)i * 589824,
                                              offwP3 + (size_t)i * 41472);

    float* out_f = (float*)d_out;
    for (int i = 0; i < 3; ++i) {
        energy_kernel<<<dim3(4, 4, BB), 256, 0, stream>>>(z[i], attn_z, Nz);
        energy_kernel<<<dim3(4, 4, BB), 256, 0, stream>>>(x[i], attn_x, Nx);
        softmax_kernel<<<BB * 256, 256, 0, stream>>>(attn_z);
        softmax_kernel<<<BB * 256, 256, 0, stream>>>(attn_x);
        cam_use_kernel<<<dim3(4, 4, BB), 256, 0, stream>>>(z[i], attn_x, gamma[i], gz, Nz);
        cam_use_kernel<<<dim3(16, 4, BB), 256, 0, stream>>>(x[i], attn_z, gamma[i], gx, Nx);

        // merged z+x offset conv (bx<16: x, else z)
        offset_kernel<<<dim3(20, BB), 256, 0, stream>>>(
            gx, gz, offwP3 + (size_t)i * 41472, offb[i], pyxx, pyz);

        float* oz = out_f + (size_t)i * ZSZ;
        float* ox = out_f + 3 * ZSZ + (size_t)i * XSZ;
        // merged z+x deform (bx<16: x, else z)
        deform_mfma_kernel<<<dim3(20, BB), 256, 0, stream>>>(
            gx, gz, WTs3 + (size_t)i * 589824, pyxx, pyz, ox, oz);
    }
}

// Round 5
// 2051.604 us; speedup vs baseline: 1.3859x; 1.1823x over previous
//
#include <hip/hip_runtime.h>
#include <math.h>

// ============================================================================
// Round 6: bisect retreat. Base = round-2 kernel (PASSED, 2425us) + EXACTLY ONE
// delta: gather lane remap in SAMPLE.
//   - OLD: lane=(pixl,cb) loads channels [cb*32,cb*32+32) -> per-lane 128B
//     STRIDE footprint -> ~64 cache lines per wave-load-instr (L1-bound).
//   - NEW: lane=(pixl,f4) loads channels f4*4+gq*32+{0..3} -> 8 lanes cover one
//     CONTIGUOUS 128B run -> 8 lines per wave-load-instr (8x fewer L1 txns).
//   - LDS content is BYTE-IDENTICAL to round 2: channel c of pixel p at
//     valq[c>>3][p][c&7]; only the writing lane + granularity (f16x4) changed.
//   - Readers / barriers / double-buffer / epilogue / launch_bounds(256,2):
//     verbatim round 2. Swizzle, XCD remap, single-buffer: DROPPED (one of the
//     round-4 bundle broke correctness; reintroduce as isolated deltas later).
// ============================================================================

#define BB 32

typedef _Float16 f16x8 __attribute__((ext_vector_type(8)));
typedef _Float16 f16x4 __attribute__((ext_vector_type(4)));
typedef float    f32x4 __attribute__((ext_vector_type(4)));

// ---------- prep: weight fragment swizzle + offset-weight transpose ----------
// WTs fragment order: for ks in [0,72), ot in [0,16), lane in [0,64), j in [0,8):
//   frag-K kk = ks*32 + (lane>>4)*8 + j, interpreted kyx-major: kyx=kk>>8, c=kk&255
//   WTs[((ks*16+ot)*64+lane)*8+j] = f16( dw[o=ot*16+(lane&15)][c][kyx] )
__global__ void prep_kernel(const float* __restrict__ dw,
                            const float* __restrict__ offw,
                            _Float16* __restrict__ WTs,   // [589824]
                            float* __restrict__ offwP) {  // [9][18][256]
    int bx = blockIdx.x;
    int t  = threadIdx.x;
    if (bx < 2304) {
        int idx = bx * 256 + t;
        int j    = idx & 7;
        int lane = (idx >> 3) & 63;
        int ot   = (idx >> 9) & 15;
        int ks   = idx >> 13;
        int o  = ot * 16 + (lane & 15);
        int kk = ks * 32 + (lane >> 4) * 8 + j;      // kyx-major K index
        int c   = kk & 255;
        int kyx = kk >> 8;
        WTs[idx] = (_Float16)dw[(size_t)o * 2304 + c * 9 + kyx];
    } else {
        int r = bx - 2304;            // [0,162): kyx*18 + j
        int kyx = r / 18, j = r % 18;
        offwP[((size_t)(kyx * 18 + j)) * 256 + t] = offw[((size_t)(j * 256 + t)) * 9 + kyx];
    }
}

// ---------- energy: E[b,c,d] = sum_n f[c,n] f[d,n] ----------
__global__ void energy_kernel(const float* __restrict__ f,
                              float* __restrict__ energy, int N) {
    int b  = blockIdx.z;
    int c0 = blockIdx.x * 64;
    int d0 = blockIdx.y * 64;
    int t  = threadIdx.x;
    __shared__ __align__(16) float A[32][68];
    __shared__ __align__(16) float Bs[32][68];
    float acc[4][4] = {};
    int cc0 = (t & 15) * 4;
    int dd0 = (t >> 4) * 4;
    const float* fb = f + (size_t)b * 256 * N;
    for (int n0 = 0; n0 < N; n0 += 32) {
        #pragma unroll
        for (int pass = 0; pass < 8; ++pass) {
            int idx = pass * 256 + t;
            int nn = idx & 31;
            int rr = idx >> 5;
            int n = n0 + nn;
            float va = (n < N) ? fb[(size_t)(c0 + rr) * N + n] : 0.f;
            float vb = (n < N) ? fb[(size_t)(d0 + rr) * N + n] : 0.f;
            A[nn][rr]  = va;
            Bs[nn][rr] = vb;
        }
        __syncthreads();
        #pragma unroll 8
        for (int nn = 0; nn < 32; ++nn) {
            float4 a4 = *(const float4*)&A[nn][cc0];
            float4 b4 = *(const float4*)&Bs[nn][dd0];
            float av[4] = {a4.x, a4.y, a4.z, a4.w};
            float bv[4] = {b4.x, b4.y, b4.z, b4.w};
            #pragma unroll
            for (int i = 0; i < 4; ++i)
                #pragma unroll
                for (int j = 0; j < 4; ++j)
                    acc[i][j] += av[i] * bv[j];
        }
        __syncthreads();
    }
    #pragma unroll
    for (int i = 0; i < 4; ++i) {
        float4 o4 = {acc[i][0], acc[i][1], acc[i][2], acc[i][3]};
        *(float4*)&energy[((size_t)b * 256 + (c0 + cc0 + i)) * 256 + d0 + dd0] = o4;
    }
}

// ---------- softmax over rows: attn = exp(min - e) / sum ----------
__global__ void softmax_kernel(float* __restrict__ attn) {
    int row = blockIdx.x;
    int t = threadIdx.x;
    float e = attn[(size_t)row * 256 + t];
    __shared__ float red[256];
    red[t] = e;
    __syncthreads();
    for (int s = 128; s > 0; s >>= 1) {
        if (t < s) red[t] = fminf(red[t], red[t + s]);
        __syncthreads();
    }
    float mn = red[0];
    __syncthreads();
    float p = __expf(mn - e);
    red[t] = p;
    __syncthreads();
    for (int s = 128; s > 0; s >>= 1) {
        if (t < s) red[t] += red[t + s];
        __syncthreads();
    }
    float inv = 1.f / red[0];
    attn[(size_t)row * 256 + t] = p * inv;
}

// ---------- cam_use (cross attn), channel-last output ----------
__global__ void cam_use_kernel(const float* __restrict__ f,
                               const float* __restrict__ attn,
                               const float* __restrict__ gamma,
                               float* __restrict__ g, int N) {
    int b  = blockIdx.z;
    int n0 = blockIdx.x * 64;
    int c0 = blockIdx.y * 64;
    int t  = threadIdx.x;
    __shared__ __align__(16) float At[32][68];
    __shared__ __align__(16) float Ft[32][68];
    float acc[4][4] = {};
    int cc0 = (t & 15) * 4;
    int nn0 = (t >> 4) * 4;
    const float* fb = f + (size_t)b * 256 * N;
    const float* ab = attn + (size_t)b * 256 * 256;
    for (int d0 = 0; d0 < 256; d0 += 32) {
        #pragma unroll
        for (int pass = 0; pass < 8; ++pass) {
            int idx = pass * 256 + t;
            int dd = idx & 31;
            int cc = idx >> 5;
            At[dd][cc] = ab[(size_t)(c0 + cc) * 256 + d0 + dd];
        }
        #pragma unroll
        for (int pass = 0; pass < 8; ++pass) {
            int idx = pass * 256 + t;
            int nn = idx & 63;
            int dd = idx >> 6;
            int n = n0 + nn;
            Ft[dd][nn] = (n < N) ? fb[(size_t)(d0 + dd) * N + n] : 0.f;
        }
        __syncthreads();
        #pragma unroll 8
        for (int dd = 0; dd < 32; ++dd) {
            float4 a4 = *(const float4*)&At[dd][cc0];
            float4 f4 = *(const float4*)&Ft[dd][nn0];
            float av[4] = {a4.x, a4.y, a4.z, a4.w};
            float fv[4] = {f4.x, f4.y, f4.z, f4.w};
            #pragma unroll
            for (int i = 0; i < 4; ++i)
                #pragma unroll
                for (int j = 0; j < 4; ++j)
                    acc[i][j] += av[i] * fv[j];
        }
        __syncthreads();
    }
    float gam = gamma[0];
    #pragma unroll
    for (int j = 0; j < 4; ++j) {
        int n = n0 + nn0 + j;
        if (n >= N) continue;
        float4 o4;
        o4.x = fb[(size_t)(c0 + cc0 + 0) * N + n] + gam * acc[0][j];
        o4.y = fb[(size_t)(c0 + cc0 + 1) * N + n] + gam * acc[1][j];
        o4.z = fb[(size_t)(c0 + cc0 + 2) * N + n] + gam * acc[2][j];
        o4.w = fb[(size_t)(c0 + cc0 + 3) * N + n] + gam * acc[3][j];
        *(float4*)&g[((size_t)b * N + n) * 256 + c0 + cc0] = o4;
    }
}

// ---------- offset conv: pyx[b][pix][18] = base + conv18(g), z+x merged ----------
__global__ void offset_kernel(const float* __restrict__ gx_,
                              const float* __restrict__ gz_,
                              const float* __restrict__ offwP,   // [9][18][256]
                              const float* __restrict__ offb,    // [18]
                              float* __restrict__ pyxx_,
                              float* __restrict__ pyxz_) {
    const int bx = blockIdx.x;
    const float* g; float* pyxg; int H, W, p0;
    if (bx < 16) { g = gx_; pyxg = pyxx_; H = 31; W = 31; p0 = bx * 64; }
    else         { g = gz_; pyxg = pyxz_; H = 15; W = 15; p0 = (bx - 16) * 64; }
    const int N = H * W;
    const int b  = blockIdx.y;
    const int t  = threadIdx.x;
    const int pixl = t & 63;
    const int q = __builtin_amdgcn_readfirstlane(t >> 6);  // channel quarter
    const int pix = p0 + pixl;
    float acc[18];
    #pragma unroll
    for (int j = 0; j < 18; ++j) acc[j] = 0.f;
    const float* gb = g + (size_t)b * N * 256;
    if (pix < N) {
        int h = pix / W, w_ = pix % W;
        for (int kyx = 0; kyx < 9; ++kyx) {
            int y = h + kyx / 3 - 1;
            int x = w_ + kyx % 3 - 1;
            if (y < 0 || y >= H || x < 0 || x >= W) continue;
            const float* grow = gb + (size_t)(y * W + x) * 256 + q * 64;
            const float* wrow = offwP + (size_t)kyx * 18 * 256 + q * 64;
            for (int c4 = 0; c4 < 16; ++c4) {
                float4 g4 = *(const float4*)(grow + c4 * 4);
                #pragma unroll
                for (int j = 0; j < 18; ++j) {
                    float4 w4 = *(const float4*)(wrow + (size_t)j * 256 + c4 * 4);
                    acc[j] += g4.x * w4.x + g4.y * w4.y + g4.z * w4.z + g4.w * w4.w;
                }
            }
        }
    }
    __shared__ float red[4][64][18];
    #pragma unroll
    for (int j = 0; j < 18; ++j) red[q][pixl][j] = acc[j];
    __syncthreads();
    for (int idx = t; idx < 64 * 18; idx += 256) {
        int pl = idx / 18, j = idx % 18;
        int pp = p0 + pl;
        if (pp >= N) continue;
        float s = red[0][pl][j] + red[1][pl][j] + red[2][pl][j] + red[3][pl][j] + offb[j];
        int k = j >> 1, comp = j & 1;
        int h = pp / W, w_ = pp % W;
        float base = comp ? (float)(w_ + (k % 3) - 1) : (float)(h + (k / 3) - 1);
        pyxg[((size_t)b * N + pp) * 18 + j] = base + s;
    }
}

// ---------- deform: kyx-major K, double-buffered sample->MFMA pipeline ----------
__global__ __launch_bounds__(256, 2)
void deform_mfma_kernel(const float* __restrict__ gx_,
                        const float* __restrict__ gz_,
                        const _Float16* __restrict__ WTs,   // frag order, kyx-major K
                        const float* __restrict__ pyxx_,
                        const float* __restrict__ pyxz_,
                        float* __restrict__ outx_,
                        float* __restrict__ outz_) {
    const int bx = blockIdx.x;
    const int b  = blockIdx.y;
    const float* g; const float* pyxg; float* out; int H, W, p0;
    if (bx < 16) { g = gx_; pyxg = pyxx_; out = outx_; H = 31; W = 31; p0 = bx * 64; }
    else         { g = gz_; pyxg = pyxz_; out = outz_; H = 15; W = 15; p0 = (bx - 16) * 64; }
    const int N = H * W;
    const int t    = threadIdx.x;
    const int lane = t & 63;
    const int wv   = t >> 6;

    // LDS: 2x32KB value tiles + 13.8KB meta = 77.5KB -> 2 blocks/CU
    __shared__ __align__(16) _Float16 valq[2][32 * 64 * 8];  // [kk8][pixl][8]
    __shared__ __align__(16) float4  metaW[576];   // per (pixl,kyx): w00,w01,w10,w11
    __shared__ __align__(8)  ushort4 metaR[576];   // per (pixl,kyx): 4 clamped row idx

    const float* gb = g + (size_t)b * N * 256;
    const float Hm1 = (float)(H - 1), Wm1 = (float)(W - 1);

    // ---- metadata phase: one pass, reused by all 9 kyx iterations ----
    for (int idx = t; idx < 576; idx += 256) {
        int pixl = idx / 9, kyx = idx - pixl * 9;
        int pix = p0 + pixl;
        float py = -1.0e6f, px = -1.0e6f;
        if (pix < N) {
            const float* pp = pyxg + ((size_t)b * N + pix) * 18 + kyx * 2;
            py = pp[0]; px = pp[1];
        }
        float y0f = floorf(py), x0f = floorf(px);
        float fy = py - y0f, fx = px - x0f;
        bool vy0 = (y0f >= 0.f) && (y0f <= Hm1);
        bool vy1 = (y0f + 1.f >= 0.f) && (y0f + 1.f <= Hm1);
        bool vx0 = (x0f >= 0.f) && (x0f <= Wm1);
        bool vx1 = (x0f + 1.f >= 0.f) && (x0f + 1.f <= Wm1);
        int iy0 = min(max((int)y0f, 0), H - 1);
        int iy1 = min(max((int)y0f + 1, 0), H - 1);
        int ix0 = min(max((int)x0f, 0), W - 1);
        int ix1 = min(max((int)x0f + 1, 0), W - 1);
        float w00 = (vy0 && vx0) ? (1.f - fy) * (1.f - fx) : 0.f;
        float w01 = (vy0 && vx1) ? (1.f - fy) * fx : 0.f;
        float w10 = (vy1 && vx0) ? fy * (1.f - fx) : 0.f;
        float w11 = (vy1 && vx1) ? fy * fx : 0.f;
        metaW[idx] = make_float4(w00, w01, w10, w11);
        metaR[idx] = make_ushort4((unsigned short)(iy0 * W + ix0),
                                  (unsigned short)(iy0 * W + ix1),
                                  (unsigned short)(iy1 * W + ix0),
                                  (unsigned short)(iy1 * W + ix1));
    }

    f32x4 acc[4][4];
    #pragma unroll
    for (int i = 0; i < 4; ++i)
        #pragma unroll
        for (int j = 0; j < 4; ++j)
            acc[i][j] = (f32x4){0.f, 0.f, 0.f, 0.f};

    // sample one kyx plane (64px x 256ch) into valq[bufsel].
    // NEW lane map: thread=(pixl=item>>3, f4=item&7); 8 lanes (same pixl) cover
    // one contiguous 128B run per bilinear row per gq -> 8 cache lines per
    // wave-load-instr instead of 64. Channels per thread: c = f4*4 + gq*32 + j.
    // Store c at valq[c>>3][pixl][c&7] -- IDENTICAL layout to round 2.
    auto SAMPLE = [&](int kyx, int bufsel) {
        _Float16* vq = &valq[bufsel][0];
        #pragma unroll
        for (int s = 0; s < 2; ++s) {
            int item = t + s * 256;          // 512 items: (pixl, f4)
            int pixl = item >> 3;
            int f4   = item & 7;
            float4  w4 = metaW[pixl * 9 + kyx];
            ushort4 r4 = metaR[pixl * 9 + kyx];
            const float* p00 = gb + (size_t)r4.x * 256 + f4 * 4;
            const float* p01 = gb + (size_t)r4.y * 256 + f4 * 4;
            const float* p10 = gb + (size_t)r4.z * 256 + f4 * 4;
            const float* p11 = gb + (size_t)r4.w * 256 + f4 * 4;
            const int halfoff = (f4 & 1) * 4;
            const int kk8base = f4 >> 1;
            #pragma unroll
            for (int gq = 0; gq < 8; ++gq) {
                float4 a  = *(const float4*)(p00 + gq * 32);
                float4 bq = *(const float4*)(p01 + gq * 32);
                float4 cq = *(const float4*)(p10 + gq * 32);
                float4 dq = *(const float4*)(p11 + gq * 32);
                f16x4 h;
                h[0] = (_Float16)(w4.x * a.x + w4.y * bq.x + w4.z * cq.x + w4.w * dq.x);
                h[1] = (_Float16)(w4.x * a.y + w4.y * bq.y + w4.z * cq.y + w4.w * dq.y);
                h[2] = (_Float16)(w4.x * a.z + w4.y * bq.z + w4.z * cq.z + w4.w * dq.z);
                h[3] = (_Float16)(w4.x * a.w + w4.y * bq.w + w4.z * cq.w + w4.w * dq.w);
                int kk8 = kk8base + gq * 4;
                *(f16x4*)&vq[(kk8 * 64 + pixl) * 8 + halfoff] = h;
            }
        }
    };

    // 8 K-steps (K=32 each) over one kyx plane -- verbatim round 2
    auto MFMA9 = [&](int kyx, int bufsel) {
        const _Float16* vq = &valq[bufsel][0];
        #pragma unroll 4
        for (int cs = 0; cs < 8; ++cs) {
            int ks = kyx * 8 + cs;
            f16x8 afrag[4], bfrag[4];
            #pragma unroll
            for (int ot = 0; ot < 4; ++ot)
                afrag[ot] = *(const f16x8*)(WTs +
                    (((size_t)ks * 16 + wv * 4 + ot) * 64 + lane) * 8);
            #pragma unroll
            for (int pt = 0; pt < 4; ++pt)
                bfrag[pt] = *(const f16x8*)(vq +
                    (((cs * 4 + (lane >> 4)) * 64) + pt * 16 + (lane & 15)) * 8);
            #pragma unroll
            for (int ot = 0; ot < 4; ++ot)
                #pragma unroll
                for (int pt = 0; pt < 4; ++pt)
                    acc[ot][pt] = __builtin_amdgcn_mfma_f32_16x16x32_f16(
                        afrag[ot], bfrag[pt], acc[ot][pt], 0, 0, 0);
        }
    };

    __syncthreads();          // meta visible
    SAMPLE(0, 0);
    for (int kyx = 0; kyx < 9; ++kyx) {
        __syncthreads();      // sample(kyx) complete; MFMA(kyx-1) done
        if (kyx < 8) SAMPLE(kyx + 1, (kyx + 1) & 1);  // loads in flight over MFMA
        MFMA9(kyx, kyx & 1);
    }

    // ---- epilogue: per-wave LDS transpose -> 16B coalesced stores ----
    // (verbatim round 2; wv*4096-float regions are IN-BOUNDS of the 64KB valq)
    __syncthreads();          // valq free for reuse
    float* tp = (float*)&valq[0][0] + wv * 4096;   // 64o x 64px per wave
    const int pcol = lane & 15;
    const int quad = lane >> 4;
    #pragma unroll
    for (int ot = 0; ot < 4; ++ot)
        #pragma unroll
        for (int pt = 0; pt < 4; ++pt)
            #pragma unroll
            for (int r = 0; r < 4; ++r)
                tp[(ot * 16 + quad * 4 + r) * 64 + pt * 16 + pcol] = acc[ot][pt][r];
    // per-wave region: compiler-inserted lgkmcnt handles the RAW dependency
    float* ob = out + (size_t)b * 256 * N;
    #pragma unroll
    for (int i = 0; i < 16; ++i) {
        int o   = wv * 64 + i * 4 + quad;
        int px0 = p0 + pcol * 4;
        float4 v = *(const float4*)&tp[(i * 4 + quad) * 64 + pcol * 4];
        if (px0 + 3 < N) {
            *(float4*)&ob[(size_t)o * N + px0] = v;
        } else if (px0 < N) {
            float vv[4] = {v.x, v.y, v.z, v.w};
            #pragma unroll
            for (int j = 0; j < 4; ++j)
                if (px0 + j < N) ob[(size_t)o * N + px0 + j] = vv[j];
        }
    }
}

extern "C" void kernel_launch(void* const* d_in, const int* in_sizes, int n_in,
                              void* d_out, int out_size, void* d_ws, size_t ws_size,
                              hipStream_t stream) {
    const int Nz = 225, Nx = 961;
    const size_t ZSZ = (size_t)BB * 256 * Nz;
    const size_t XSZ = (size_t)BB * 256 * Nx;

    bool dict_order = (in_sizes[1] == (int)XSZ);
    const float *z[3], *x[3], *offw[3], *offb[3], *dw[3], *gamma[3];
    for (int i = 0; i < 3; ++i) {
        if (dict_order) {
            z[i]     = (const float*)d_in[i * 6 + 0];
            x[i]     = (const float*)d_in[i * 6 + 1];
            offw[i]  = (const float*)d_in[i * 6 + 2];
            offb[i]  = (const float*)d_in[i * 6 + 3];
            dw[i]    = (const float*)d_in[i * 6 + 4];
            gamma[i] = (const float*)d_in[i * 6 + 5];
        } else {
            z[i]     = (const float*)d_in[i];
            x[i]     = (const float*)d_in[3 + i];
            offw[i]  = (const float*)d_in[6 + i * 4 + 0];
            offb[i]  = (const float*)d_in[6 + i * 4 + 1];
            dw[i]    = (const float*)d_in[6 + i * 4 + 2];
            gamma[i] = (const float*)d_in[6 + i * 4 + 3];
        }
    }

    // workspace layout (floats)
    float* ws = (float*)d_ws;
    _Float16* WTs3 = (_Float16*)ws;          // 3*589824 f16 = 884736 floats
    float* offwP3 = ws + 884736;             // 3*41472
    float* attn_z = offwP3 + 3 * 41472;      // 2097152
    float* attn_x = attn_z + 2097152;        // 2097152
    float* gz     = attn_x + 2097152;        // 1843200
    float* gx     = gz + 1843200;            // 7872512
    float* pyz    = gx + 7872512;            // 32*225*18 = 129600
    float* pyxx   = pyz + 129600;            // 32*961*18 = 553536
    // total 15,602,304 floats = 62.4 MB

    for (int i = 0; i < 3; ++i)
        prep_kernel<<<2466, 256, 0, stream>>>(dw[i], offw[i],
                                              WTs3 + (size_t)i * 589824,
                                              offwP3 + (size_t)i * 41472);

    float* out_f = (float*)d_out;
    for (int i = 0; i < 3; ++i) {
        energy_kernel<<<dim3(4, 4, BB), 256, 0, stream>>>(z[i], attn_z, Nz);
        energy_kernel<<<dim3(4, 4, BB), 256, 0, stream>>>(x[i], attn_x, Nx);
        softmax_kernel<<<BB * 256, 256, 0, stream>>>(attn_z);
        softmax_kernel<<<BB * 256, 256, 0, stream>>>(attn_x);
        cam_use_kernel<<<dim3(4, 4, BB), 256, 0, stream>>>(z[i], attn_x, gamma[i], gz, Nz);
        cam_use_kernel<<<dim3(16, 4, BB), 256, 0, stream>>>(x[i], attn_z, gamma[i], gx, Nx);

        // merged z+x offset conv (bx<16: x, else z)
        offset_kernel<<<dim3(20, BB), 256, 0, stream>>>(
            gx, gz, offwP3 + (size_t)i * 41472, offb[i], pyxx, pyz);

        float* oz = out_f + (size_t)i * ZSZ;
        float* ox = out_f + 3 * ZSZ + (size_t)i * XSZ;
        // merged z+x deform (bx<16: x, else z)
        deform_mfma_kernel<<<dim3(20, BB), 256, 0, stream>>>(
            gx, gz, WTs3 + (size_t)i * 589824, pyxx, pyz, ox, oz);
    }
}

// Round 8
// 1696.243 us; speedup vs baseline: 1.6762x; 1.2095x over previous
//
#include <hip/hip_runtime.h>
#include <math.h>

// ============================================================================
// Round 8: bisect of the round-6/7 bundle (2x container death, no diagnostics).
// Base = round-5 (PASSED, 2051us) + ONE delta: energy -> MFMA hi/lo split.
//   - XCD-chunk remap DROPPED this round (provably crash-free, but removed to
//     keep the diff minimal; returns as its own delta once this passes).
//   - energy_mfma: E ~= h.h^T + h.l^T + l.h^T with h=f16(f), l=f16(f-h);
//     error ~2e-4 absolute vs threshold 0.08. Fragment recipe = deform's
//     proven one; E is symmetric so orientation bugs are value-neutral.
//   cam_use/offset/softmax/prep/deform: verbatim round 5.
// ============================================================================

#define BB 32

typedef _Float16 f16x8 __attribute__((ext_vector_type(8)));
typedef _Float16 f16x4 __attribute__((ext_vector_type(4)));
typedef float    f32x4 __attribute__((ext_vector_type(4)));

// ---------- prep: weight fragment swizzle + offset-weight transpose ----------
__global__ void prep_kernel(const float* __restrict__ dw,
                            const float* __restrict__ offw,
                            _Float16* __restrict__ WTs,   // [589824]
                            float* __restrict__ offwP) {  // [9][18][256]
    int bx = blockIdx.x;
    int t  = threadIdx.x;
    if (bx < 2304) {
        int idx = bx * 256 + t;
        int j    = idx & 7;
        int lane = (idx >> 3) & 63;
        int ot   = (idx >> 9) & 15;
        int ks   = idx >> 13;
        int o  = ot * 16 + (lane & 15);
        int kk = ks * 32 + (lane >> 4) * 8 + j;      // kyx-major K index
        int c   = kk & 255;
        int kyx = kk >> 8;
        WTs[idx] = (_Float16)dw[(size_t)o * 2304 + c * 9 + kyx];
    } else {
        int r = bx - 2304;            // [0,162): kyx*18 + j
        int kyx = r / 18, j = r % 18;
        offwP[((size_t)(kyx * 18 + j)) * 256 + t] = offw[((size_t)(j * 256 + t)) * 9 + kyx];
    }
}

// ---------- energy via MFMA, hi/lo f16 split ----------
// E[b][c][d] = sum_n f[c,n] f[d,n].  f = h + l (h=f16(f), l=f16(f-h)).
// E ~= h_c.h_d + h_c.l_d + l_c.h_d  (drop l.l ~ 2e-4 absolute).
// Fragment recipe identical to deform's proven one:
//   A/B frag: lane&15 -> row, k = (lane>>4)*8+j ; D: col=lane&15, row=(lane>>4)*4+reg.
#define ERS 40   // f16 row stride: 80B = 16B-aligned rows, bank-balanced frag reads
__global__ __launch_bounds__(256, 4)
void energy_mfma_kernel(const float* __restrict__ f,
                        float* __restrict__ energy, int N) {
    const int b  = blockIdx.z;
    const int c0 = blockIdx.x * 64;
    const int d0 = blockIdx.y * 64;
    const int t  = threadIdx.x;
    const int lane = t & 63;
    const int wv   = t >> 6;

    __shared__ __align__(16) _Float16 Ah[64][ERS];
    __shared__ __align__(16) _Float16 Al[64][ERS];
    __shared__ __align__(16) _Float16 Bh[64][ERS];
    __shared__ __align__(16) _Float16 Bl[64][ERS];

    const float* fb = f + (size_t)b * 256 * N;

    f32x4 acc[4];
    #pragma unroll
    for (int j = 0; j < 4; ++j) acc[j] = (f32x4){0.f, 0.f, 0.f, 0.f};

    const int ra     = t >> 2;     // 0..63: staging row
    const int c4base = t & 3;      // +4s -> c4 in 0..7 (4 consecutive lanes = 64B run)

    for (int n0 = 0; n0 < N; n0 += 32) {
        __syncthreads();           // previous MFMA done reading LDS
        #pragma unroll
        for (int s = 0; s < 2; ++s) {
            int c4 = c4base + 4 * s;          // 0..7
            int n  = n0 + c4 * 4;
            const float* rowc = fb + (size_t)(c0 + ra) * N;
            const float* rowd = fb + (size_t)(d0 + ra) * N;
            float va[4], vb[4];
            if (n + 3 < N) {
                float4 t4 = *(const float4*)(rowc + n);
                va[0] = t4.x; va[1] = t4.y; va[2] = t4.z; va[3] = t4.w;
                float4 u4 = *(const float4*)(rowd + n);
                vb[0] = u4.x; vb[1] = u4.y; vb[2] = u4.z; vb[3] = u4.w;
            } else {
                #pragma unroll
                for (int k = 0; k < 4; ++k) {
                    va[k] = (n + k < N) ? rowc[n + k] : 0.f;
                    vb[k] = (n + k < N) ? rowd[n + k] : 0.f;
                }
            }
            f16x4 ha, la, hb, lb;
            #pragma unroll
            for (int k = 0; k < 4; ++k) {
                ha[k] = (_Float16)va[k];
                la[k] = (_Float16)(va[k] - (float)ha[k]);
                hb[k] = (_Float16)vb[k];
                lb[k] = (_Float16)(vb[k] - (float)hb[k]);
            }
            *(f16x4*)&Ah[ra][c4 * 4] = ha;
            *(f16x4*)&Al[ra][c4 * 4] = la;
            *(f16x4*)&Bh[ra][c4 * 4] = hb;
            *(f16x4*)&Bl[ra][c4 * 4] = lb;
        }
        __syncthreads();           // tiles staged
        const int fr = lane & 15;
        const int fq = lane >> 4;
        f16x8 a_h = *(const f16x8*)&Ah[wv * 16 + fr][fq * 8];
        f16x8 a_l = *(const f16x8*)&Al[wv * 16 + fr][fq * 8];
        #pragma unroll
        for (int pt = 0; pt < 4; ++pt) {
            f16x8 b_h = *(const f16x8*)&Bh[pt * 16 + fr][fq * 8];
            f16x8 b_l = *(const f16x8*)&Bl[pt * 16 + fr][fq * 8];
            acc[pt] = __builtin_amdgcn_mfma_f32_16x16x32_f16(a_h, b_h, acc[pt], 0, 0, 0);
            acc[pt] = __builtin_amdgcn_mfma_f32_16x16x32_f16(a_h, b_l, acc[pt], 0, 0, 0);
            acc[pt] = __builtin_amdgcn_mfma_f32_16x16x32_f16(a_l, b_h, acc[pt], 0, 0, 0);
        }
    }

    // epilogue: D col=lane&15 (d), row=(lane>>4)*4+reg (c)
    const int fr = lane & 15;
    const int fq = lane >> 4;
    #pragma unroll
    for (int pt = 0; pt < 4; ++pt)
        #pragma unroll
        for (int r = 0; r < 4; ++r)
            energy[((size_t)b * 256 + (c0 + wv * 16 + fq * 4 + r)) * 256
                   + d0 + pt * 16 + fr] = acc[pt][r];
}

// ---------- softmax over rows: attn = exp(min - e) / sum ----------
__global__ void softmax_kernel(float* __restrict__ attn) {
    int row = blockIdx.x;
    int t = threadIdx.x;
    float e = attn[(size_t)row * 256 + t];
    __shared__ float red[256];
    red[t] = e;
    __syncthreads();
    for (int s = 128; s > 0; s >>= 1) {
        if (t < s) red[t] = fminf(red[t], red[t + s]);
        __syncthreads();
    }
    float mn = red[0];
    __syncthreads();
    float p = __expf(mn - e);
    red[t] = p;
    __syncthreads();
    for (int s = 128; s > 0; s >>= 1) {
        if (t < s) red[t] += red[t + s];
        __syncthreads();
    }
    float inv = 1.f / red[0];
    attn[(size_t)row * 256 + t] = p * inv;
}

// ---------- cam_use (cross attn), channel-last output ----------
__global__ void cam_use_kernel(const float* __restrict__ f,
                               const float* __restrict__ attn,
                               const float* __restrict__ gamma,
                               float* __restrict__ g, int N) {
    int b  = blockIdx.z;
    int n0 = blockIdx.x * 64;
    int c0 = blockIdx.y * 64;
    int t  = threadIdx.x;
    __shared__ __align__(16) float At[32][68];
    __shared__ __align__(16) float Ft[32][68];
    float acc[4][4] = {};
    int cc0 = (t & 15) * 4;
    int nn0 = (t >> 4) * 4;
    const float* fb = f + (size_t)b * 256 * N;
    const float* ab = attn + (size_t)b * 256 * 256;
    for (int d0 = 0; d0 < 256; d0 += 32) {
        #pragma unroll
        for (int pass = 0; pass < 8; ++pass) {
            int idx = pass * 256 + t;
            int dd = idx & 31;
            int cc = idx >> 5;
            At[dd][cc] = ab[(size_t)(c0 + cc) * 256 + d0 + dd];
        }
        #pragma unroll
        for (int pass = 0; pass < 8; ++pass) {
            int idx = pass * 256 + t;
            int nn = idx & 63;
            int dd = idx >> 6;
            int n = n0 + nn;
            Ft[dd][nn] = (n < N) ? fb[(size_t)(d0 + dd) * N + n] : 0.f;
        }
        __syncthreads();
        #pragma unroll 8
        for (int dd = 0; dd < 32; ++dd) {
            float4 a4 = *(const float4*)&At[dd][cc0];
            float4 f4 = *(const float4*)&Ft[dd][nn0];
            float av[4] = {a4.x, a4.y, a4.z, a4.w};
            float fv[4] = {f4.x, f4.y, f4.z, f4.w};
            #pragma unroll
            for (int i = 0; i < 4; ++i)
                #pragma unroll
                for (int j = 0; j < 4; ++j)
                    acc[i][j] += av[i] * fv[j];
        }
        __syncthreads();
    }
    float gam = gamma[0];
    #pragma unroll
    for (int j = 0; j < 4; ++j) {
        int n = n0 + nn0 + j;
        if (n >= N) continue;
        float4 o4;
        o4.x = fb[(size_t)(c0 + cc0 + 0) * N + n] + gam * acc[0][j];
        o4.y = fb[(size_t)(c0 + cc0 + 1) * N + n] + gam * acc[1][j];
        o4.z = fb[(size_t)(c0 + cc0 + 2) * N + n] + gam * acc[2][j];
        o4.w = fb[(size_t)(c0 + cc0 + 3) * N + n] + gam * acc[3][j];
        *(float4*)&g[((size_t)b * N + n) * 256 + c0 + cc0] = o4;
    }
}

// ---------- offset conv: pyx[b][pix][18] = base + conv18(g), z+x merged ----------
__global__ void offset_kernel(const float* __restrict__ gx_,
                              const float* __restrict__ gz_,
                              const float* __restrict__ offwP,   // [9][18][256]
                              const float* __restrict__ offb,    // [18]
                              float* __restrict__ pyxx_,
                              float* __restrict__ pyxz_) {
    const int bx = blockIdx.x;
    const float* g; float* pyxg; int H, W, p0;
    if (bx < 16) { g = gx_; pyxg = pyxx_; H = 31; W = 31; p0 = bx * 64; }
    else         { g = gz_; pyxg = pyxz_; H = 15; W = 15; p0 = (bx - 16) * 64; }
    const int N = H * W;
    const int b  = blockIdx.y;
    const int t  = threadIdx.x;
    const int pixl = t & 63;
    const int q = __builtin_amdgcn_readfirstlane(t >> 6);  // channel quarter
    const int pix = p0 + pixl;
    float acc[18];
    #pragma unroll
    for (int j = 0; j < 18; ++j) acc[j] = 0.f;
    const float* gb = g + (size_t)b * N * 256;
    if (pix < N) {
        int h = pix / W, w_ = pix % W;
        for (int kyx = 0; kyx < 9; ++kyx) {
            int y = h + kyx / 3 - 1;
            int x = w_ + kyx % 3 - 1;
            if (y < 0 || y >= H || x < 0 || x >= W) continue;
            const float* grow = gb + (size_t)(y * W + x) * 256 + q * 64;
            const float* wrow = offwP + (size_t)kyx * 18 * 256 + q * 64;
            for (int c4 = 0; c4 < 16; ++c4) {
                float4 g4 = *(const float4*)(grow + c4 * 4);
                #pragma unroll
                for (int j = 0; j < 18; ++j) {
                    float4 w4 = *(const float4*)(wrow + (size_t)j * 256 + c4 * 4);
                    acc[j] += g4.x * w4.x + g4.y * w4.y + g4.z * w4.z + g4.w * w4.w;
                }
            }
        }
    }
    __shared__ float red[4][64][18];
    #pragma unroll
    for (int j = 0; j < 18; ++j) red[q][pixl][j] = acc[j];
    __syncthreads();
    for (int idx = t; idx < 64 * 18; idx += 256) {
        int pl = idx / 18, j = idx % 18;
        int pp = p0 + pl;
        if (pp >= N) continue;
        float s = red[0][pl][j] + red[1][pl][j] + red[2][pl][j] + red[3][pl][j] + offb[j];
        int k = j >> 1, comp = j & 1;
        int h = pp / W, w_ = pp % W;
        float base = comp ? (float)(w_ + (k % 3) - 1) : (float)(h + (k / 3) - 1);
        pyxg[((size_t)b * N + pp) * 18 + j] = base + s;
    }
}

// ---------- deform: kyx-major K, double-buffered sample->MFMA pipeline ----------
__global__ __launch_bounds__(256, 2)
void deform_mfma_kernel(const float* __restrict__ gx_,
                        const float* __restrict__ gz_,
                        const _Float16* __restrict__ WTs,   // frag order, kyx-major K
                        const float* __restrict__ pyxx_,
                        const float* __restrict__ pyxz_,
                        float* __restrict__ outx_,
                        float* __restrict__ outz_) {
    const int bx = blockIdx.x;
    const int b  = blockIdx.y;
    const float* g; const float* pyxg; float* out; int H, W, p0;
    if (bx < 16) { g = gx_; pyxg = pyxx_; out = outx_; H = 31; W = 31; p0 = bx * 64; }
    else         { g = gz_; pyxg = pyxz_; out = outz_; H = 15; W = 15; p0 = (bx - 16) * 64; }
    const int N = H * W;
    const int t    = threadIdx.x;
    const int lane = t & 63;
    const int wv   = t >> 6;

    // LDS: 2x32KB value tiles + 13.8KB meta = 77.5KB -> 2 blocks/CU
    __shared__ __align__(16) _Float16 valq[2][32 * 64 * 8];  // [kk8][pixl][8]
    __shared__ __align__(16) float4  metaW[576];   // per (pixl,kyx): w00,w01,w10,w11
    __shared__ __align__(8)  ushort4 metaR[576];   // per (pixl,kyx): 4 clamped row idx

    const float* gb = g + (size_t)b * N * 256;
    const float Hm1 = (float)(H - 1), Wm1 = (float)(W - 1);

    // ---- metadata phase: one pass, reused by all 9 kyx iterations ----
    for (int idx = t; idx < 576; idx += 256) {
        int pixl = idx / 9, kyx = idx - pixl * 9;
        int pix = p0 + pixl;
        float py = -1.0e6f, px = -1.0e6f;
        if (pix < N) {
            const float* pp = pyxg + ((size_t)b * N + pix) * 18 + kyx * 2;
            py = pp[0]; px = pp[1];
        }
        float y0f = floorf(py), x0f = floorf(px);
        float fy = py - y0f, fx = px - x0f;
        bool vy0 = (y0f >= 0.f) && (y0f <= Hm1);
        bool vy1 = (y0f + 1.f >= 0.f) && (y0f + 1.f <= Hm1);
        bool vx0 = (x0f >= 0.f) && (x0f <= Wm1);
        bool vx1 = (x0f + 1.f >= 0.f) && (x0f + 1.f <= Wm1);
        int iy0 = min(max((int)y0f, 0), H - 1);
        int iy1 = min(max((int)y0f + 1, 0), H - 1);
        int ix0 = min(max((int)x0f, 0), W - 1);
        int ix1 = min(max((int)x0f + 1, 0), W - 1);
        float w00 = (vy0 && vx0) ? (1.f - fy) * (1.f - fx) : 0.f;
        float w01 = (vy0 && vx1) ? (1.f - fy) * fx : 0.f;
        float w10 = (vy1 && vx0) ? fy * (1.f - fx) : 0.f;
        float w11 = (vy1 && vx1) ? fy * fx : 0.f;
        metaW[idx] = make_float4(w00, w01, w10, w11);
        metaR[idx] = make_ushort4((unsigned short)(iy0 * W + ix0),
                                  (unsigned short)(iy0 * W + ix1),
                                  (unsigned short)(iy1 * W + ix0),
                                  (unsigned short)(iy1 * W + ix1));
    }

    f32x4 acc[4][4];
    #pragma unroll
    for (int i = 0; i < 4; ++i)
        #pragma unroll
        for (int j = 0; j < 4; ++j)
            acc[i][j] = (f32x4){0.f, 0.f, 0.f, 0.f};

    // sample one kyx plane (64px x 256ch) into valq[bufsel].
    // lane map: (pixl=item>>3, f4=item&7); 8 lanes cover one contiguous 128B
    // run per bilinear row per gq. c = f4*4 + gq*32 + j; store at
    // valq[c>>3][pixl][c&7] (layout identical to round 2).
    auto SAMPLE = [&](int kyx, int bufsel) {
        _Float16* vq = &valq[bufsel][0];
        #pragma unroll
        for (int s = 0; s < 2; ++s) {
            int item = t + s * 256;          // 512 items: (pixl, f4)
            int pixl = item >> 3;
            int f4   = item & 7;
            float4  w4 = metaW[pixl * 9 + kyx];
            ushort4 r4 = metaR[pixl * 9 + kyx];
            const float* p00 = gb + (size_t)r4.x * 256 + f4 * 4;
            const float* p01 = gb + (size_t)r4.y * 256 + f4 * 4;
            const float* p10 = gb + (size_t)r4.z * 256 + f4 * 4;
            const float* p11 = gb + (size_t)r4.w * 256 + f4 * 4;
            const int halfoff = (f4 & 1) * 4;
            const int kk8base = f4 >> 1;
            #pragma unroll
            for (int gq = 0; gq < 8; ++gq) {
                float4 a  = *(const float4*)(p00 + gq * 32);
                float4 bq = *(const float4*)(p01 + gq * 32);
                float4 cq = *(const float4*)(p10 + gq * 32);
                float4 dq = *(const float4*)(p11 + gq * 32);
                f16x4 h;
                h[0] = (_Float16)(w4.x * a.x + w4.y * bq.x + w4.z * cq.x + w4.w * dq.x);
                h[1] = (_Float16)(w4.x * a.y + w4.y * bq.y + w4.z * cq.y + w4.w * dq.y);
                h[2] = (_Float16)(w4.x * a.z + w4.y * bq.z + w4.z * cq.z + w4.w * dq.z);
                h[3] = (_Float16)(w4.x * a.w + w4.y * bq.w + w4.z * cq.w + w4.w * dq.w);
                int kk8 = kk8base + gq * 4;
                *(f16x4*)&vq[(kk8 * 64 + pixl) * 8 + halfoff] = h;
            }
        }
    };

    // 8 K-steps (K=32 each) over one kyx plane
    auto MFMA9 = [&](int kyx, int bufsel) {
        const _Float16* vq = &valq[bufsel][0];
        #pragma unroll 4
        for (int cs = 0; cs < 8; ++cs) {
            int ks = kyx * 8 + cs;
            f16x8 afrag[4], bfrag[4];
            #pragma unroll
            for (int ot = 0; ot < 4; ++ot)
                afrag[ot] = *(const f16x8*)(WTs +
                    (((size_t)ks * 16 + wv * 4 + ot) * 64 + lane) * 8);
            #pragma unroll
            for (int pt = 0; pt < 4; ++pt)
                bfrag[pt] = *(const f16x8*)(vq +
                    (((cs * 4 + (lane >> 4)) * 64) + pt * 16 + (lane & 15)) * 8);
            #pragma unroll
            for (int ot = 0; ot < 4; ++ot)
                #pragma unroll
                for (int pt = 0; pt < 4; ++pt)
                    acc[ot][pt] = __builtin_amdgcn_mfma_f32_16x16x32_f16(
                        afrag[ot], bfrag[pt], acc[ot][pt], 0, 0, 0);
        }
    };

    __syncthreads();          // meta visible
    SAMPLE(0, 0);
    for (int kyx = 0; kyx < 9; ++kyx) {
        __syncthreads();      // sample(kyx) complete; MFMA(kyx-1) done
        if (kyx < 8) SAMPLE(kyx + 1, (kyx + 1) & 1);  // loads in flight over MFMA
        MFMA9(kyx, kyx & 1);
    }

    // ---- epilogue: per-wave LDS transpose -> 16B coalesced stores ----
    __syncthreads();          // valq free for reuse
    float* tp = (float*)&valq[0][0] + wv * 4096;   // 64o x 64px per wave
    const int pcol = lane & 15;
    const int quad = lane >> 4;
    #pragma unroll
    for (int ot = 0; ot < 4; ++ot)
        #pragma unroll
        for (int pt = 0; pt < 4; ++pt)
            #pragma unroll
            for (int r = 0; r < 4; ++r)
                tp[(ot * 16 + quad * 4 + r) * 64 + pt * 16 + pcol] = acc[ot][pt][r];
    // per-wave region: compiler-inserted lgkmcnt handles the RAW dependency
    float* ob = out + (size_t)b * 256 * N;
    #pragma unroll
    for (int i = 0; i < 16; ++i) {
        int o   = wv * 64 + i * 4 + quad;
        int px0 = p0 + pcol * 4;
        float4 v = *(const float4*)&tp[(i * 4 + quad) * 64 + pcol * 4];
        if (px0 + 3 < N) {
            *(float4*)&ob[(size_t)o * N + px0] = v;
        } else if (px0 < N) {
            float vv[4] = {v.x, v.y, v.z, v.w};
            #pragma unroll
            for (int j = 0; j < 4; ++j)
                if (px0 + j < N) ob[(size_t)o * N + px0 + j] = vv[j];
        }
    }
}

extern "C" void kernel_launch(void* const* d_in, const int* in_sizes, int n_in,
                              void* d_out, int out_size, void* d_ws, size_t ws_size,
                              hipStream_t stream) {
    const int Nz = 225, Nx = 961;
    const size_t ZSZ = (size_t)BB * 256 * Nz;
    const size_t XSZ = (size_t)BB * 256 * Nx;

    bool dict_order = (in_sizes[1] == (int)XSZ);
    const float *z[3], *x[3], *offw[3], *offb[3], *dw[3], *gamma[3];
    for (int i = 0; i < 3; ++i) {
        if (dict_order) {
            z[i]     = (const float*)d_in[i * 6 + 0];
            x[i]     = (const float*)d_in[i * 6 + 1];
            offw[i]  = (const float*)d_in[i * 6 + 2];
            offb[i]  = (const float*)d_in[i * 6 + 3];
            dw[i]    = (const float*)d_in[i * 6 + 4];
            gamma[i] = (const float*)d_in[i * 6 + 5];
        } else {
            z[i]     = (const float*)d_in[i];
            x[i]     = (const float*)d_in[3 + i];
            offw[i]  = (const float*)d_in[6 + i * 4 + 0];
            offb[i]  = (const float*)d_in[6 + i * 4 + 1];
            dw[i]    = (const float*)d_in[6 + i * 4 + 2];
            gamma[i] = (const float*)d_in[6 + i * 4 + 3];
        }
    }

    // workspace layout (floats)
    float* ws = (float*)d_ws;
    _Float16* WTs3 = (_Float16*)ws;          // 3*589824 f16 = 884736 floats
    float* offwP3 = ws + 884736;             // 3*41472
    float* attn_z = offwP3 + 3 * 41472;      // 2097152
    float* attn_x = attn_z + 2097152;        // 2097152
    float* gz     = attn_x + 2097152;        // 1843200
    float* gx     = gz + 1843200;            // 7872512
    float* pyz    = gx + 7872512;            // 32*225*18 = 129600
    float* pyxx   = pyz + 129600;            // 32*961*18 = 553536
    // total 15,602,304 floats = 62.4 MB

    for (int i = 0; i < 3; ++i)
        prep_kernel<<<2466, 256, 0, stream>>>(dw[i], offw[i],
                                              WTs3 + (size_t)i * 589824,
                                              offwP3 + (size_t)i * 41472);

    float* out_f = (float*)d_out;
    for (int i = 0; i < 3; ++i) {
        energy_mfma_kernel<<<dim3(4, 4, BB), 256, 0, stream>>>(z[i], attn_z, Nz);
        energy_mfma_kernel<<<dim3(4, 4, BB), 256, 0, stream>>>(x[i], attn_x, Nx);
        softmax_kernel<<<BB * 256, 256, 0, stream>>>(attn_z);
        softmax_kernel<<<BB * 256, 256, 0, stream>>>(attn_x);
        cam_use_kernel<<<dim3(4, 4, BB), 256, 0, stream>>>(z[i], attn_x, gamma[i], gz, Nz);
        cam_use_kernel<<<dim3(16, 4, BB), 256, 0, stream>>>(x[i], attn_z, gamma[i], gx, Nx);

        // merged z+x offset conv (bx<16: x, else z)
        offset_kernel<<<dim3(20, BB), 256, 0, stream>>>(
            gx, gz, offwP3 + (size_t)i * 41472, offb[i], pyxx, pyz);

        float* oz = out_f + (size_t)i * ZSZ;
        float* ox = out_f + 3 * ZSZ + (size_t)i * XSZ;
        // merged z+x deform (bx<16: x, else z)
        deform_mfma_kernel<<<dim3(20, BB), 256, 0, stream>>>(
            gx, gz, WTs3 + (size_t)i * 589824, pyxx, pyz, ox, oz);
    }
}